// Round 13
// baseline (391.897 us; speedup 1.0000x reference)
//
#include <hip/hip_runtime.h>

#define T_LEN 1024
#define P_DIM 32
#define HOME_IDX 0
#define NCHUNK 32
#define CHUNK 32

// One wave (lanes 0-63) per batch; 1024 threads/block exist only for the
// parallel chunked backtrack (waves 1-15 sleep at the post-loop barrier).
//
// THIS round's single change vs the r10 PROVEN base (245 us): the delta
// broadcast moves from LDS (write + 8x uniform ds_read_b128 round trip,
// measured ~400+ cy on the serial chain across r10/r12) to SGPRs:
//   * 32x v_readlane_b32 (constant lane indices) re-materialize the full
//     wave-uniform delta vector each step — VALU issue only, NO DS pipe,
//     no LDS latency on the value chain.
//   * candidates: v_add_f32 c[q] = s[q] + Acol[q] (one SGPR read per VALU
//     instruction — architecturally legal).
//   * value path: 32 rl + 32 add + max3 tree + selects — pure VALU.
//   * index path: r7-PROVEN full-32 descending equality scan vs v1
//     (ia init 0, j=31..0, overwrite => first/min matching q; fmax returns
//     an input bit-exactly; +-0 compare equal; inputs NaN-free).
//     psi write unconditional, both halves identical bytes (r7-proven).
//   * remaining DS per step (both OFF the value chain): u0 __shfl
//     (r4-proven, prepared one step early) + 1 psi ds_write_u8.
//   * readlane is in the proven-safe instruction family; permlane/DPP
//     remain banned (r2/r3/r5/r6 isolation).
//
// Exactness notes (harness-verified across rounds):
//  * NEG = finfo(f32).min/4; NEG + A == NEG (ulp(NEG) >> |A|<=0.01) -> the
//    v=0 slice collapses to v0 = delta0h + A[0][p], a0 = 0 exactly.
//  * use1 = (v1 > v0) strict; cond = use1 || is_home;
//    psi byte = cond ? (a1|32) : 0.
//  * delta0h update order preserved: (delta0h + A00) + (u[t,0] + bias0).
//
// Backtrack (PROVEN round 4): 1023 backsteps in 32 chunks of <=32.
// Phase 1: 1024 threads build per-chunk (y,v)-maps for all 32 v=1 entry
// states. Phase 2: one thread composes maps from (last_p,1); v=0 absorbing
// at (0,0). Phase 3: 32 lanes re-walk their chunk from its true entry.
// Per-backstep rule identical to serial: if v: (y,v)=(byte&31,(byte>>5)&1)
// else (0,0); out[i] = new y.

__launch_bounds__(1024, 1)
__global__ void crf_viterbi_kernel(const float* __restrict__ U,
                                   const float* __restrict__ A,
                                   const float* __restrict__ bias,
                                   int* __restrict__ out)
{
    __shared__ unsigned char spsi[(T_LEN - 1) * P_DIM];   // 32736 B
    __shared__ unsigned char Mmap[NCHUNK * P_DIM];        // chunk maps
    __shared__ unsigned char ent[NCHUNK];                 // chunk entry states
    __shared__ int last_p_sh;

    const int tid = threadIdx.x;
    const int b   = blockIdx.x;
    int* __restrict__ outb = out + (size_t)b * T_LEN;

    if (tid < 64) {
        const int lane = tid;
        const int p    = lane & 31;
        const float NEG = -(3.4028234663852886e38f / 4.0f);

        // Full A column: Acol[q] = A[q][p], q = 0..31
        float Acol[32];
#pragma unroll
        for (int q = 0; q < 32; ++q)
            Acol[q] = A[q * P_DIM + p];
        const float A00    = A[0];        // A[HOME][HOME]
        const float bias_p = bias[p];
        const float bias0  = bias[0];
        const bool  is_home = (p == HOME_IDX);

        const float* __restrict__ Ub = U + (size_t)b * T_LEN * P_DIM;

        // t = 0 init
        const float u00 = Ub[p] + bias_p;
        float delta1  = is_home ? NEG : u00;     // v=1 slice, per-lane p
        float delta0h = Ub[HOME_IDX] + bias0;    // v=0 slice at HOME (uniform)

        // Prefetch ring, depth 4. Row t lives in slot (t-1)&3.
        float L0 = Ub[1 * P_DIM + p];
        float L1 = Ub[2 * P_DIM + p];
        float L2 = Ub[3 * P_DIM + p];
        float L3 = Ub[4 * P_DIM + p];

        float Ut_n = L0 + bias_p;          // for t = 1
        float u0_n = __shfl(Ut_n, 0);      // u[t,0] + bias0, broadcast

#define STEP(t, Lc, Lr) do {                                                   \
    const float Ut  = Ut_n;                                                    \
    const float u0c = u0_n;                                                    \
    Ut_n = (Lc) + bias_p;                                                      \
    u0_n = __shfl(Ut_n, 0);                                                    \
    { int tn = (t) + 4; if (tn > T_LEN - 1) tn = T_LEN - 1;                    \
      (Lr) = Ub[(size_t)tn * P_DIM + p]; }                                     \
    /* SGPR broadcast of the wave-uniform delta vector: 32 readlanes */        \
    const int dsrc = __float_as_int(delta1);                                   \
    float c[32];                                                               \
    _Pragma("unroll")                                                          \
    for (int q = 0; q < 32; ++q)                                               \
        c[q] = __int_as_float(__builtin_amdgcn_readlane(dsrc, q)) + Acol[q];   \
    /* lane-local max over all 32 (v_max3-friendly groups of 3, r7 text) */    \
    const float g0 = fmaxf(fmaxf(c[0],  c[1]),  c[2]);                         \
    const float g1 = fmaxf(fmaxf(c[3],  c[4]),  c[5]);                         \
    const float g2 = fmaxf(fmaxf(c[6],  c[7]),  c[8]);                         \
    const float g3 = fmaxf(fmaxf(c[9],  c[10]), c[11]);                        \
    const float g4 = fmaxf(fmaxf(c[12], c[13]), c[14]);                        \
    const float g5 = fmaxf(fmaxf(c[15], c[16]), c[17]);                        \
    const float g6 = fmaxf(fmaxf(c[18], c[19]), c[20]);                        \
    const float g7 = fmaxf(fmaxf(c[21], c[22]), c[23]);                        \
    const float g8 = fmaxf(fmaxf(c[24], c[25]), c[26]);                        \
    const float g9 = fmaxf(fmaxf(c[27], c[28]), c[29]);                        \
    const float m0 = fmaxf(fmaxf(g0, g1), g2);                                 \
    const float m1 = fmaxf(fmaxf(g3, g4), g5);                                 \
    const float m2 = fmaxf(fmaxf(g6, g7), g8);                                 \
    const float m3 = fmaxf(fmaxf(g9, c[30]), c[31]);                           \
    const float v1 = fmaxf(fmaxf(m0, m1), fmaxf(m2, m3));                      \
    const float v0 = delta0h + Acol[0];                                        \
    const bool  use1 = (v1 > v0);              /* strict, as reference */      \
    const bool  cond = use1 || is_home;                                        \
    const float sel  = cond ? v1 : v0;                                         \
    const float dn1  = sel + Ut;                                               \
    delta0h = (delta0h + A00) + u0c;                                           \
    /* argmax (r7-proven): first j with c[j] == v1 via descending overwrite */ \
    int ia = 0;                                                                \
    _Pragma("unroll")                                                          \
    for (int j = 31; j >= 0; --j)                                              \
        if (c[j] == v1) ia = j;                                                \
    spsi[(size_t)((t) - 1) * P_DIM + p] =                                      \
        (unsigned char)(cond ? (ia | 32) : 0);                                 \
    delta1 = dn1;                                                              \
} while (0)

        STEP(1, L1, L0);
        STEP(2, L2, L1);
        STEP(3, L3, L2);
        for (int t = 4; t <= T_LEN - 4; t += 4) {
            STEP(t + 0, L0, L3);
            STEP(t + 1, L1, L0);
            STEP(t + 2, L2, L1);
            STEP(t + 3, L3, L2);
        }
#undef STEP

        // last_p = argmax_p delta_T[:,1], first index wins (proven butterfly;
        // lanes 32..63 duplicate p = lane-32, idx tie-break handles them).
        float mv = delta1;
        int   mi = p;
#pragma unroll
        for (int m = 16; m >= 1; m >>= 1) {
            float ov = __shfl_xor(mv, m);
            int   oi = __shfl_xor(mi, m);
            bool take = (ov > mv) || ((ov == mv) && (oi < mi));
            mv = take ? ov : mv;
            mi = take ? oi : mi;
        }
        if (lane == 0) {
            outb[T_LEN - 1] = mi;
            last_p_sh = mi;
        }
    }

    __syncthreads();   // psi + last_p visible to all 16 waves

    // Phase 1: per-chunk maps. Chunk c covers backsteps i in
    // [32c, min(32c+32, 1023)). Thread (c = tid>>5, pp = tid&31) walks from
    // hypothetical entry (pp, v=1).
    {
        const int c  = tid >> 5;
        const int pp = tid & 31;
        const int i_hi = min((c + 1) * CHUNK, T_LEN - 1);
        const int i_lo = c * CHUNK;
        int y = pp, v = 1;
        for (int i = i_hi - 1; i >= i_lo; --i) {
            const int bt = spsi[i * P_DIM + y];
            const int py = v ? (bt & 31) : 0;
            const int nv = v ? ((bt >> 5) & 1) : 0;
            y = py; v = nv;
        }
        Mmap[c * P_DIM + pp] = (unsigned char)(y | (v << 5));
    }
    __syncthreads();

    // Phase 2: compose maps from the top to get each chunk's true entry state.
    if (tid == 0) {
        int y = last_p_sh, v = 1;
        for (int c = NCHUNK - 1; c >= 0; --c) {
            ent[c] = (unsigned char)(y | (v << 5));
            if (v) {
                const int m = Mmap[c * P_DIM + y];
                y = m & 31;
                v = (m >> 5) & 1;
            } else {
                y = 0; v = 0;
            }
        }
    }
    __syncthreads();

    // Phase 3: 32 lanes re-walk their chunk from the true entry, emitting out.
    if (tid < NCHUNK) {
        const int c = tid;
        const int i_hi = min((c + 1) * CHUNK, T_LEN - 1);
        const int i_lo = c * CHUNK;
        const int e = ent[c];
        int y = e & 31;
        int v = (e >> 5) & 1;
        for (int i = i_hi - 1; i >= i_lo; --i) {
            const int bt = spsi[i * P_DIM + y];
            const int py = v ? (bt & 31) : 0;
            const int nv = v ? ((bt >> 5) & 1) : 0;
            outb[i] = py;
            y = py; v = nv;
        }
    }
}

extern "C" void kernel_launch(void* const* d_in, const int* in_sizes, int n_in,
                              void* d_out, int out_size, void* d_ws, size_t ws_size,
                              hipStream_t stream) {
    const float* U    = (const float*)d_in[0];   // (B, T, P) f32
    const float* A    = (const float*)d_in[1];   // (P, P)    f32
    const float* bias = (const float*)d_in[2];   // (P,)      f32
    int* out = (int*)d_out;                      // (B, T)    int32

    const int B = in_sizes[0] / (T_LEN * P_DIM);
    crf_viterbi_kernel<<<B, 1024, 0, stream>>>(U, A, bias, out);
}

// Round 14
// 304.505 us; speedup vs baseline: 1.2870x; 1.2870x over previous
//
#include <hip/hip_runtime.h>

#define T_LEN 1024
#define P_DIM 32
#define HOME_IDX 0
#define NCHUNK 32
#define CHUNK 32

// One wave (lanes 0-63) per batch; 1024 threads/block exist only for the
// parallel chunked backtrack (waves 1-15 sleep at the post-loop barrier).
//
// Base = r10 PROVEN kernel (245 us): LDS-restage delta broadcast (1
// ds_write_b32 + 4 uniform ds_read_b128, in-order DS pipe, no barrier) +
// 16-q-per-half split + r11-proven local-scan/combine index path.
//
// THIS round: same instructions, REORDERED under the in-order-issue model.
// Waves issue strictly in program order, so latency is hidden only by work
// textually placed between a DS op's issue and its first consume. Two-stage
// psi pipeline:
//   stage A (at step t):  scan step t-1's candidates vs its LOCAL bvp
//                         (shfl-independent, r11-proven semantics) -> ia1;
//                         issue shfl_xor(ia1). This fills shfl(bv)'s stall.
//   stage B (at step t):  step t-2's combine (r11-proven: bv2>ovv2 ? ia2
//                         : io2; tie -> min = half-0's index) + psi write —
//                         operands arrived long ago, zero stall.
// Epilogue flushes s = T-2 and s = T-1.
//
// Exactness notes (harness-verified across rounds):
//  * NEG = finfo(f32).min/4; NEG + A == NEG (ulp(NEG) >> |A|<=0.01) -> the
//    v=0 slice collapses to v0 = delta0h + A[0][p], a0 = 0 exactly.
//  * use1 = (v1 > v0) strict; cond = use1 || is_home;
//    psi byte = cond ? (a1|32) : 0.
//  * local scan: CP[j]==bvp, descending j, init q0+15 -> FIRST matching local
//    index (fmax returns an input bit-exactly; +-0 compare equal; NaN-free).
//  * combine: a1 = bv2>ovv2 ? ia2 : io2, tie -> min(ia2,io2) => first-index.
//  * delta0h update order preserved: (delta0h + A00) + (u[t,0] + bias0).
//
// Backtrack (PROVEN round 4): 1023 backsteps in 32 chunks of <=32.
// Phase 1: 1024 threads build per-chunk (y,v)-maps for all 32 v=1 entry
// states. Phase 2: one thread composes maps from (last_p,1); v=0 absorbing
// at (0,0). Phase 3: 32 lanes re-walk their chunk from its true entry.

__launch_bounds__(1024, 1)
__global__ void crf_viterbi_kernel(const float* __restrict__ U,
                                   const float* __restrict__ A,
                                   const float* __restrict__ bias,
                                   int* __restrict__ out)
{
    __shared__ __align__(16) float sdelta[P_DIM];         // 128 B delta stage
    __shared__ unsigned char spsi[(T_LEN - 1) * P_DIM];   // 32736 B
    __shared__ unsigned char Mmap[NCHUNK * P_DIM];        // chunk maps
    __shared__ unsigned char ent[NCHUNK];                 // chunk entry states
    __shared__ int last_p_sh;

    const int tid = threadIdx.x;
    const int b   = blockIdx.x;
    int* __restrict__ outb = out + (size_t)b * T_LEN;

    if (tid < 64) {
        const int lane = tid;
        const int p    = lane & 31;
        const int h    = lane >> 5;
        const float NEG = -(3.4028234663852886e38f / 4.0f);

        // A fragment: A[q][p] for q = 16*h + j
        float Areg[16];
#pragma unroll
        for (int j = 0; j < 16; ++j)
            Areg[j] = A[(16 * h + j) * P_DIM + p];
        const float A0p    = A[p];        // A[HOME][p]
        const float A00    = A[0];        // A[HOME][HOME]
        const float bias_p = bias[p];
        const float bias0  = bias[0];
        const int   q0     = h << 4;      // first q of this half
        const bool  is_home = (p == HOME_IDX);

        const float4* __restrict__ sd4 = (const float4*)sdelta;
        const float* __restrict__ Ub = U + (size_t)b * T_LEN * P_DIM;

        // t = 0 init
        const float u00 = Ub[p] + bias_p;
        float delta1  = is_home ? NEG : u00;     // v=1 slice, per-lane p
        float delta0h = Ub[HOME_IDX] + bias0;    // v=0 slice at HOME (uniform)

        // Prefetch ring, depth 4. Row t lives in slot (t-1)&3.
        float L0 = Ub[1 * P_DIM + p];
        float L1 = Ub[2 * P_DIM + p];
        float L2 = Ub[3 * P_DIM + p];
        float L3 = Ub[4 * P_DIM + p];

        float Ut_n = L0 + bias_p;          // for t = 1
        float u0_n = __shfl(Ut_n, 0);      // u[t,0] + bias0, broadcast

        // Stage initial delta; read this half's 16 q's (in-order DS pipe).
        sdelta[p] = delta1;
        float4 R0 = sd4[4 * h + 0];
        float4 R1 = sd4[4 * h + 1];
        float4 R2 = sd4[4 * h + 2];
        float4 R3 = sd4[4 * h + 3];

        // psi pipeline state
        float cA[16], cB[16];
        float bvp = 0.f, ovvp = 0.f, bv2 = 0.f, ovv2 = 0.f;
        bool  condp = false, cond2 = false;
        int   ia2 = 0, io2 = 0;

#define STEP(t, F1, F2, CC, CP, Lc, Lr) do {                                   \
    const float Ut  = Ut_n;                                                    \
    const float u0c = u0_n;                                                    \
    CC[0]  = R0.x + Areg[0];  CC[1]  = R0.y + Areg[1];                         \
    CC[2]  = R0.z + Areg[2];  CC[3]  = R0.w + Areg[3];                         \
    CC[4]  = R1.x + Areg[4];  CC[5]  = R1.y + Areg[5];                         \
    CC[6]  = R1.z + Areg[6];  CC[7]  = R1.w + Areg[7];                         \
    CC[8]  = R2.x + Areg[8];  CC[9]  = R2.y + Areg[9];                         \
    CC[10] = R2.z + Areg[10]; CC[11] = R2.w + Areg[11];                        \
    CC[12] = R3.x + Areg[12]; CC[13] = R3.y + Areg[13];                        \
    CC[14] = R3.z + Areg[14]; CC[15] = R3.w + Areg[15];                        \
    const float g0 = fmaxf(fmaxf(CC[0],  CC[1]),  CC[2]);                      \
    const float g1 = fmaxf(fmaxf(CC[3],  CC[4]),  CC[5]);                      \
    const float g2 = fmaxf(fmaxf(CC[6],  CC[7]),  CC[8]);                      \
    const float g3 = fmaxf(fmaxf(CC[9],  CC[10]), CC[11]);                     \
    const float g4 = fmaxf(fmaxf(CC[12], CC[13]), CC[14]);                     \
    const float h0 = fmaxf(fmaxf(g0, g1), g2);                                 \
    const float h1 = fmaxf(fmaxf(g3, g4), CC[15]);                             \
    const float bv = fmaxf(h0, h1);                                            \
    /* issue the value exchange NOW; fill its stall with stage A + B */        \
    const float ovv = __shfl_xor(bv, 32);                                      \
    int ia1 = 0, io1 = 0;                                                      \
    if (F1) {   /* stage A: scan step t-1 vs its LOCAL bvp (r11-proven) */     \
        ia1 = q0 + 15;                                                         \
        _Pragma("unroll")                                                      \
        for (int j = 14; j >= 0; --j)                                          \
            if (CP[j] == bvp) ia1 = q0 + j;                                    \
        io1 = __shfl_xor(ia1, 32);                                             \
    }                                                                          \
    if (F2) {   /* stage B: combine + psi write for step t-2 (zero stall) */   \
        const int amin = (ia2 < io2) ? ia2 : io2;                              \
        int a1 = (bv2 > ovv2) ? ia2 : io2;                                     \
        a1 = (bv2 == ovv2) ? amin : a1;                                        \
        spsi[(size_t)((t) - 3) * P_DIM + p] =                                  \
            (unsigned char)(cond2 ? (a1 | 32) : 0);                            \
    }                                                                          \
    const float v1 = fmaxf(bv, ovv);           /* ovv arrived during fill */   \
    const float v0 = delta0h + A0p;                                            \
    const bool  use1 = (v1 > v0);              /* strict, as reference */      \
    const bool  cond = use1 || is_home;                                        \
    const float sel  = cond ? v1 : v0;                                         \
    const float dn1  = sel + Ut;                                               \
    delta0h = (delta0h + A00) + u0c;                                           \
    /* restage delta + issue next step's reads (in-order DS, no barrier) */    \
    sdelta[p] = dn1;                                                           \
    R0 = sd4[4 * h + 0];                                                       \
    R1 = sd4[4 * h + 1];                                                       \
    R2 = sd4[4 * h + 2];                                                       \
    R3 = sd4[4 * h + 3];                                                       \
    /* tail glue fills part of the read latency */                             \
    Ut_n = (Lc) + bias_p;                                                      \
    u0_n = __shfl(Ut_n, 0);                                                    \
    { int tn = (t) + 4; if (tn > T_LEN - 1) tn = T_LEN - 1;                    \
      (Lr) = Ub[(size_t)tn * P_DIM + p]; }                                     \
    /* rotate pipeline */                                                      \
    bv2 = bvp; ovv2 = ovvp; cond2 = condp;                                     \
    ia2 = ia1; io2 = io1;                                                      \
    bvp = bv; ovvp = ovv; condp = cond;                                        \
    delta1 = dn1;                                                              \
} while (0)

        STEP(1, 0, 0, cA, cB, L1, L0);
        STEP(2, 1, 0, cB, cA, L2, L1);
        STEP(3, 1, 1, cA, cB, L3, L2);
        for (int t = 4; t <= T_LEN - 4; t += 4) {
            STEP(t + 0, 1, 1, cB, cA, L0, L3);
            STEP(t + 1, 1, 1, cA, cB, L1, L0);
            STEP(t + 2, 1, 1, cB, cA, L2, L1);
            STEP(t + 3, 1, 1, cA, cB, L3, L2);
        }
#undef STEP

        // Epilogue: flush pending psi stages.
        {   // s = T_LEN-2 (depth-2 regs hold its data after the last rotate)
            const int amin = (ia2 < io2) ? ia2 : io2;
            int a1 = (bv2 > ovv2) ? ia2 : io2;
            a1 = (bv2 == ovv2) ? amin : a1;
            spsi[(size_t)(T_LEN - 3) * P_DIM + p] =
                (unsigned char)(cond2 ? (a1 | 32) : 0);
        }
        {   // s = T_LEN-1 (last step, odd -> its candidates live in cA)
            int ia = q0 + 15;
#pragma unroll
            for (int j = 14; j >= 0; --j)
                if (cA[j] == bvp) ia = q0 + j;
            const int oia  = __shfl_xor(ia, 32);
            const int amin = (ia < oia) ? ia : oia;
            int a1 = (bvp > ovvp) ? ia : oia;
            a1 = (bvp == ovvp) ? amin : a1;
            spsi[(size_t)(T_LEN - 2) * P_DIM + p] =
                (unsigned char)(condp ? (a1 | 32) : 0);
        }

        // last_p = argmax_p delta_T[:,1], first index wins (proven butterfly;
        // lanes 32..63 duplicate p = lane-32, idx tie-break handles them).
        float mv = delta1;
        int   mi = p;
#pragma unroll
        for (int m = 16; m >= 1; m >>= 1) {
            float ov = __shfl_xor(mv, m);
            int   oi = __shfl_xor(mi, m);
            bool take = (ov > mv) || ((ov == mv) && (oi < mi));
            mv = take ? ov : mv;
            mi = take ? oi : mi;
        }
        if (lane == 0) {
            outb[T_LEN - 1] = mi;
            last_p_sh = mi;
        }
    }

    __syncthreads();   // psi + last_p visible to all 16 waves

    // Phase 1: per-chunk maps. Chunk c covers backsteps i in
    // [32c, min(32c+32, 1023)). Thread (c = tid>>5, pp = tid&31) walks from
    // hypothetical entry (pp, v=1).
    {
        const int c  = tid >> 5;
        const int pp = tid & 31;
        const int i_hi = min((c + 1) * CHUNK, T_LEN - 1);
        const int i_lo = c * CHUNK;
        int y = pp, v = 1;
        for (int i = i_hi - 1; i >= i_lo; --i) {
            const int bt = spsi[i * P_DIM + y];
            const int py = v ? (bt & 31) : 0;
            const int nv = v ? ((bt >> 5) & 1) : 0;
            y = py; v = nv;
        }
        Mmap[c * P_DIM + pp] = (unsigned char)(y | (v << 5));
    }
    __syncthreads();

    // Phase 2: compose maps from the top to get each chunk's true entry state.
    if (tid == 0) {
        int y = last_p_sh, v = 1;
        for (int c = NCHUNK - 1; c >= 0; --c) {
            ent[c] = (unsigned char)(y | (v << 5));
            if (v) {
                const int m = Mmap[c * P_DIM + y];
                y = m & 31;
                v = (m >> 5) & 1;
            } else {
                y = 0; v = 0;
            }
        }
    }
    __syncthreads();

    // Phase 3: 32 lanes re-walk their chunk from the true entry, emitting out.
    if (tid < NCHUNK) {
        const int c = tid;
        const int i_hi = min((c + 1) * CHUNK, T_LEN - 1);
        const int i_lo = c * CHUNK;
        const int e = ent[c];
        int y = e & 31;
        int v = (e >> 5) & 1;
        for (int i = i_hi - 1; i >= i_lo; --i) {
            const int bt = spsi[i * P_DIM + y];
            const int py = v ? (bt & 31) : 0;
            const int nv = v ? ((bt >> 5) & 1) : 0;
            outb[i] = py;
            y = py; v = nv;
        }
    }
}

extern "C" void kernel_launch(void* const* d_in, const int* in_sizes, int n_in,
                              void* d_out, int out_size, void* d_ws, size_t ws_size,
                              hipStream_t stream) {
    const float* U    = (const float*)d_in[0];   // (B, T, P) f32
    const float* A    = (const float*)d_in[1];   // (P, P)    f32
    const float* bias = (const float*)d_in[2];   // (P,)      f32
    int* out = (int*)d_out;                      // (B, T)    int32

    const int B = in_sizes[0] / (T_LEN * P_DIM);
    crf_viterbi_kernel<<<B, 1024, 0, stream>>>(U, A, bias, out);
}